// Round 1
// baseline (225.149 us; speedup 1.0000x reference)
//
#include <hip/hip_runtime.h>

#define NUM_NETS     100000
#define PINS_PER_NET 5
#define NUM_PINS     (NUM_NETS * PINS_PER_NET)
#define NB           512
#define BIN_H        1.953125f          /* 1000/512, exact in fp32 */
#define INV_H        0.512f             /* 512/1000 */
#define OUT_SCALE    (1.0f / 195.3125f) /* 1/(BIN_SIZE_X * 100 tracks) */

// ---------------------------------------------------------------------------
// Kernel 1: per-net bbox -> 4x4 (+/-) corner stencil scatter into difference
// grids U_h, U_v (512x512 each). h_map = 2D inclusive prefix-sum of U_h.
// ---------------------------------------------------------------------------
__global__ void scatter_kernel(const float* __restrict__ pin_pos,
                               const int*   __restrict__ flat_netpin,
                               const float* __restrict__ net_weights,
                               float* __restrict__ Uh,
                               float* __restrict__ Uv) {
    int n = blockIdx.x * blockDim.x + threadIdx.x;
    if (n >= NUM_NETS) return;

    float xmn = 1e30f, xmx = -1e30f, ymn = 1e30f, ymx = -1e30f;
#pragma unroll
    for (int p = 0; p < PINS_PER_NET; ++p) {
        int pi  = flat_netpin[n * PINS_PER_NET + p];
        float x = pin_pos[pi];
        float y = pin_pos[NUM_PINS + pi];
        xmn = fminf(xmn, x); xmx = fmaxf(xmx, x);
        ymn = fminf(ymn, y); ymx = fmaxf(ymx, y);
    }
    float w  = net_weights[n];
    float wh = w / (ymx - ymn);   // horizontal demand weight
    float wv = w / (xmx - xmn);   // vertical demand weight

    int kx1 = min(NB - 1, (int)(xmn * INV_H));
    int kx2 = min(NB - 1, (int)(xmx * INV_H));
    int ky1 = min(NB - 1, (int)(ymn * INV_H));
    int ky2 = min(NB - 1, (int)(ymx * INV_H));

    // second-difference stencil of (ramp(e - min) - ramp(e - max))
    int   xi[4] = { kx1, kx1 + 1, kx2, kx2 + 1 };
    float xv[4] = { (kx1 + 1) * BIN_H - xmn,  xmn - kx1 * BIN_H,
                    -((kx2 + 1) * BIN_H - xmx), -(xmx - kx2 * BIN_H) };
    int   yi[4] = { ky1, ky1 + 1, ky2, ky2 + 1 };
    float yv[4] = { (ky1 + 1) * BIN_H - ymn,  ymn - ky1 * BIN_H,
                    -((ky2 + 1) * BIN_H - ymx), -(ymx - ky2 * BIN_H) };

#pragma unroll
    for (int a = 0; a < 4; ++a) {
        if (xi[a] >= NB) continue;          // index 512 never affects output bins
#pragma unroll
        for (int b = 0; b < 4; ++b) {
            if (yi[b] >= NB) continue;
            float prod = xv[a] * yv[b];
            int   idx  = xi[a] * NB + yi[b];
            atomicAdd(&Uh[idx], wh * prod);
            atomicAdd(&Uv[idx], wv * prod);
        }
    }
}

// ---------------------------------------------------------------------------
// Kernel 2: inclusive scan along the contiguous (y) dimension, one block/row.
// ---------------------------------------------------------------------------
__global__ void row_scan_kernel(float* __restrict__ Uh, float* __restrict__ Uv) {
    __shared__ float sh[NB];
    __shared__ float sv[NB];
    int r = blockIdx.x;
    int t = threadIdx.x;
    sh[t] = Uh[r * NB + t];
    sv[t] = Uv[r * NB + t];
    __syncthreads();
#pragma unroll
    for (int off = 1; off < NB; off <<= 1) {
        float a = (t >= off) ? sh[t - off] : 0.0f;
        float b = (t >= off) ? sv[t - off] : 0.0f;
        __syncthreads();
        sh[t] += a;
        sv[t] += b;
        __syncthreads();
    }
    Uh[r * NB + t] = sh[t];
    Uv[r * NB + t] = sv[t];
}

// ---------------------------------------------------------------------------
// Kernel 3: running sum down columns (x dimension) + fused epilogue:
// out = clip(max(|h|,|v|)^2, 0.5, 2.0). Coalesced across threads (columns).
// ---------------------------------------------------------------------------
__global__ void col_scan_finish_kernel(const float* __restrict__ Uh,
                                       const float* __restrict__ Uv,
                                       float* __restrict__ out) {
    int t = blockIdx.x * blockDim.x + threadIdx.x;  // column = by
    if (t >= NB) return;
    float sh = 0.0f, sv = 0.0f;
    for (int i = 0; i < NB; ++i) {
        sh += Uh[i * NB + t];
        sv += Uv[i * NB + t];
        float h = fabsf(sh) * OUT_SCALE;
        float v = fabsf(sv) * OUT_SCALE;
        float r = fmaxf(h, v);
        out[i * NB + t] = fminf(fmaxf(r * r, 0.5f), 2.0f);
    }
}

extern "C" void kernel_launch(void* const* d_in, const int* in_sizes, int n_in,
                              void* d_out, int out_size, void* d_ws, size_t ws_size,
                              hipStream_t stream) {
    const float* pin_pos     = (const float*)d_in[0];
    /* d_in[1] = netpin_start: implicit (uniform 5 pins/net), unused */
    const int*   flat_netpin = (const int*)d_in[2];
    const float* net_weights = (const float*)d_in[3];

    float* Uh = (float*)d_ws;
    float* Uv = Uh + NB * NB;

    hipMemsetAsync(d_ws, 0, 2 * NB * NB * sizeof(float), stream);

    scatter_kernel<<<(NUM_NETS + 255) / 256, 256, 0, stream>>>(
        pin_pos, flat_netpin, net_weights, Uh, Uv);

    row_scan_kernel<<<NB, NB, 0, stream>>>(Uh, Uv);

    col_scan_finish_kernel<<<2, 256, 0, stream>>>(Uh, Uv, (float*)d_out);
}

// Round 2
// 116.641 us; speedup vs baseline: 1.9303x; 1.9303x over previous
//
#include <hip/hip_runtime.h>

#define NUM_NETS     100000
#define PINS_PER_NET 5
#define NUM_PINS     (NUM_NETS * PINS_PER_NET)
#define NB           512
#define BIN_H        1.953125f          /* 1000/512, exact in fp32 */
#define INV_H        0.512f             /* 512/1000 */
#define OUT_SCALE    (1.0f / 195.3125f) /* 1/(BIN_SIZE_X * 100 tracks) */

#define TILE         64                 /* bins per tile side */
#define NTX          (NB / TILE)        /* 8 */
#define NTILES       (NTX * NTX)        /* 64 */
#define STRIPE       8                  /* rows per column-scan stripe */
#define NSTRIPE      (NB / STRIPE)      /* 64 */

// ---------------------------------------------------------------------------
// K1: per-net bbox -> 32B record {xmn,xmx,ymn,ymx, wh,wv,_,_}
// ---------------------------------------------------------------------------
__global__ void bbox_kernel(const float* __restrict__ pin_pos,
                            const int*   __restrict__ flat_netpin,
                            const float* __restrict__ net_weights,
                            float4* __restrict__ rec) {
    int n = blockIdx.x * blockDim.x + threadIdx.x;
    if (n >= NUM_NETS) return;
    float xmn = 1e30f, xmx = -1e30f, ymn = 1e30f, ymx = -1e30f;
#pragma unroll
    for (int p = 0; p < PINS_PER_NET; ++p) {
        int pi  = flat_netpin[n * PINS_PER_NET + p];
        float x = pin_pos[pi];
        float y = pin_pos[NUM_PINS + pi];
        xmn = fminf(xmn, x); xmx = fmaxf(xmx, x);
        ymn = fminf(ymn, y); ymx = fmaxf(ymx, y);
    }
    float w = net_weights[n];
    rec[2 * n]     = make_float4(xmn, xmx, ymn, ymx);
    rec[2 * n + 1] = make_float4(w / (ymx - ymn), w / (xmx - xmn), 0.0f, 0.0f);
}

// ---------------------------------------------------------------------------
// K2: LDS-privatized tile accumulation. Block = (slice r, tile t).
// Tile = 64x64 bins; corner-stencil points tested against tile bounds;
// hits accumulated with LDS atomics; tile flushed with plain float4 stores.
// ---------------------------------------------------------------------------
__global__ __launch_bounds__(256) void tile_accum_kernel(
        const float4* __restrict__ rec,
        float* __restrict__ reps, int nets_per_slice) {
    __shared__ float tile[2][TILE * TILE];          /* [H/V][lx*64+ly] 32 KB */
    int t  = blockIdx.x & (NTILES - 1);
    int r  = blockIdx.x >> 6;
    int tx0 = (t >> 3) * TILE;
    int ty0 = (t & 7) * TILE;

    float4* tf4 = (float4*)&tile[0][0];
#pragma unroll
    for (int k = threadIdx.x; k < 2 * TILE * TILE / 4; k += 256)
        tf4[k] = make_float4(0.f, 0.f, 0.f, 0.f);
    __syncthreads();

    int n0 = r * nets_per_slice;
    int n1 = min(n0 + nets_per_slice, NUM_NETS);
    for (int n = n0 + (int)threadIdx.x; n < n1; n += 256) {
        float4 r0 = rec[2 * n];
        float4 r1 = rec[2 * n + 1];
        float xmn = r0.x, xmx = r0.y, ymn = r0.z, ymx = r0.w;
        float wh = r1.x, wv = r1.y;
        int kx1 = min(NB - 1, (int)(xmn * INV_H));
        int kx2 = min(NB - 1, (int)(xmx * INV_H));
        int ky1 = min(NB - 1, (int)(ymn * INV_H));
        int ky2 = min(NB - 1, (int)(ymx * INV_H));
        int   xi[4] = { kx1, kx1 + 1, kx2, kx2 + 1 };
        float xv[4] = { (kx1 + 1) * BIN_H - xmn,  xmn - kx1 * BIN_H,
                        xmx - (kx2 + 1) * BIN_H,  kx2 * BIN_H - xmx };
        int   yi[4] = { ky1, ky1 + 1, ky2, ky2 + 1 };
        float yv[4] = { (ky1 + 1) * BIN_H - ymn,  ymn - ky1 * BIN_H,
                        ymx - (ky2 + 1) * BIN_H,  ky2 * BIN_H - ymx };
#pragma unroll
        for (int a = 0; a < 4; ++a) {
            unsigned gx = (unsigned)(xi[a] - tx0);
            if (gx >= TILE) continue;
#pragma unroll
            for (int b = 0; b < 4; ++b) {
                unsigned gy = (unsigned)(yi[b] - ty0);
                if (gy >= TILE) continue;
                float prod = xv[a] * yv[b];
                int   idx  = (int)gx * TILE + (int)gy;
                atomicAdd(&tile[0][idx], wh * prod);
                atomicAdd(&tile[1][idx], wv * prod);
            }
        }
    }
    __syncthreads();

    float4* dst = (float4*)(reps + (size_t)blockIdx.x * (2 * TILE * TILE));
#pragma unroll
    for (int k = threadIdx.x; k < 2 * TILE * TILE / 4; k += 256)
        dst[k] = tf4[k];
}

// ---------------------------------------------------------------------------
// K3: reduce replicas + inclusive scan along y (contiguous). Block = grid row.
// ---------------------------------------------------------------------------
__global__ void reduce_rowscan_kernel(const float* __restrict__ reps,
                                      float* __restrict__ Uh,
                                      float* __restrict__ Uv, int R) {
    __shared__ float sh[NB];
    __shared__ float sv[NB];
    int x  = blockIdx.x;
    int tid = threadIdx.x;                 /* = y */
    int tx = x >> 6, xr = x & (TILE - 1);
    int tl = tx * NTX + (tid >> 6);        /* tile index */
    int off = xr * TILE + (tid & (TILE - 1));
    float h = 0.f, v = 0.f;
    for (int r = 0; r < R; ++r) {
        const float* base = reps + (size_t)(r * NTILES + tl) * (2 * TILE * TILE);
        h += base[off];
        v += base[TILE * TILE + off];
    }
    sh[tid] = h; sv[tid] = v;
    __syncthreads();
#pragma unroll
    for (int o = 1; o < NB; o <<= 1) {
        float a = (tid >= o) ? sh[tid - o] : 0.0f;
        float b = (tid >= o) ? sv[tid - o] : 0.0f;
        __syncthreads();
        sh[tid] += a; sv[tid] += b;
        __syncthreads();
    }
    Uh[x * NB + tid] = sh[tid];
    Uv[x * NB + tid] = sv[tid];
}

// ---------------------------------------------------------------------------
// K4: column-scan stage 1 — per-stripe (8 rows) partial inclusive scans
// (in place) + stripe totals. Fully coalesced; block = stripe.
// ---------------------------------------------------------------------------
__global__ void colscan_partial_kernel(float* __restrict__ Uh,
                                       float* __restrict__ Uv,
                                       float* __restrict__ totH,
                                       float* __restrict__ totV) {
    int s = blockIdx.x, t = threadIdx.x;   /* t = column */
    float h = 0.f, v = 0.f;
#pragma unroll
    for (int i = 0; i < STRIPE; ++i) {
        int row = s * STRIPE + i;
        h += Uh[row * NB + t];  Uh[row * NB + t] = h;
        v += Uv[row * NB + t];  Uv[row * NB + t] = v;
    }
    totH[s * NB + t] = h;
    totV[s * NB + t] = v;
}

// ---------------------------------------------------------------------------
// K5: column-scan stage 2 — add exclusive stripe offsets + fused epilogue:
// out = clip(max(|h|,|v|)^2, 0.5, 2.0)
// ---------------------------------------------------------------------------
__global__ void colscan_finish_kernel(const float* __restrict__ Uh,
                                      const float* __restrict__ Uv,
                                      const float* __restrict__ totH,
                                      const float* __restrict__ totV,
                                      float* __restrict__ out) {
    int s = blockIdx.x, t = threadIdx.x;
    float offh = 0.f, offv = 0.f;
    for (int s2 = 0; s2 < s; ++s2) {
        offh += totH[s2 * NB + t];
        offv += totV[s2 * NB + t];
    }
#pragma unroll
    for (int i = 0; i < STRIPE; ++i) {
        int row = s * STRIPE + i;
        float h = fabsf(Uh[row * NB + t] + offh) * OUT_SCALE;
        float v = fabsf(Uv[row * NB + t] + offv) * OUT_SCALE;
        float r = fmaxf(h, v);
        out[row * NB + t] = fminf(fmaxf(r * r, 0.5f), 2.0f);
    }
}

// ---------------------------------------------------------------------------
// Fallback path (tiny workspace): global-atomic scatter (R0 version)
// ---------------------------------------------------------------------------
__global__ void scatter_kernel(const float* __restrict__ pin_pos,
                               const int*   __restrict__ flat_netpin,
                               const float* __restrict__ net_weights,
                               float* __restrict__ Uh,
                               float* __restrict__ Uv) {
    int n = blockIdx.x * blockDim.x + threadIdx.x;
    if (n >= NUM_NETS) return;
    float xmn = 1e30f, xmx = -1e30f, ymn = 1e30f, ymx = -1e30f;
#pragma unroll
    for (int p = 0; p < PINS_PER_NET; ++p) {
        int pi  = flat_netpin[n * PINS_PER_NET + p];
        float x = pin_pos[pi];
        float y = pin_pos[NUM_PINS + pi];
        xmn = fminf(xmn, x); xmx = fmaxf(xmx, x);
        ymn = fminf(ymn, y); ymx = fmaxf(ymx, y);
    }
    float w  = net_weights[n];
    float wh = w / (ymx - ymn), wv = w / (xmx - xmn);
    int kx1 = min(NB - 1, (int)(xmn * INV_H));
    int kx2 = min(NB - 1, (int)(xmx * INV_H));
    int ky1 = min(NB - 1, (int)(ymn * INV_H));
    int ky2 = min(NB - 1, (int)(ymx * INV_H));
    int   xi[4] = { kx1, kx1 + 1, kx2, kx2 + 1 };
    float xv[4] = { (kx1 + 1) * BIN_H - xmn,  xmn - kx1 * BIN_H,
                    xmx - (kx2 + 1) * BIN_H,  kx2 * BIN_H - xmx };
    int   yi[4] = { ky1, ky1 + 1, ky2, ky2 + 1 };
    float yv[4] = { (ky1 + 1) * BIN_H - ymn,  ymn - ky1 * BIN_H,
                    ymx - (ky2 + 1) * BIN_H,  ky2 * BIN_H - ymx };
#pragma unroll
    for (int a = 0; a < 4; ++a) {
        if (xi[a] >= NB) continue;
#pragma unroll
        for (int b = 0; b < 4; ++b) {
            if (yi[b] >= NB) continue;
            float prod = xv[a] * yv[b];
            int   idx  = xi[a] * NB + yi[b];
            atomicAdd(&Uh[idx], wh * prod);
            atomicAdd(&Uv[idx], wv * prod);
        }
    }
}

extern "C" void kernel_launch(void* const* d_in, const int* in_sizes, int n_in,
                              void* d_out, int out_size, void* d_ws, size_t ws_size,
                              hipStream_t stream) {
    const float* pin_pos     = (const float*)d_in[0];
    const int*   flat_netpin = (const int*)d_in[2];
    const float* net_weights = (const float*)d_in[3];
    float* out = (float*)d_out;
    float* ws  = (float*)d_ws;

    /* workspace layout (floats):
       rec[NUM_NETS*8] | Uh[NB*NB] | Uv[NB*NB] | totH[NSTRIPE*NB] |
       totV[NSTRIPE*NB] | reps[R*NTILES*2*TILE*TILE]                      */
    const size_t REC   = (size_t)NUM_NETS * 8;
    const size_t GRID  = (size_t)NB * NB;
    const size_t TOT   = (size_t)NSTRIPE * NB;
    const size_t REP1  = (size_t)NTILES * 2 * TILE * TILE;   /* 512K floats */
    const size_t fixed = REC + 2 * GRID + 2 * TOT;

    int R = 0;
    if (ws_size >= (fixed + 4 * REP1) * sizeof(float))      R = 4;
    else if (ws_size >= (fixed + REP1) * sizeof(float))     R = 1;

    if (R == 0) {
        /* tiny-workspace fallback: global-atomic scatter */
        float* Uh = ws;
        float* Uv = ws + GRID;
        float* totH = Uv + GRID;
        float* totV = totH + TOT;
        hipMemsetAsync(ws, 0, 2 * GRID * sizeof(float), stream);
        scatter_kernel<<<(NUM_NETS + 255) / 256, 256, 0, stream>>>(
            pin_pos, flat_netpin, net_weights, Uh, Uv);
        /* reuse row-scan via reduce_rowscan with R=0 won't work; do scans */
        colscan_partial_kernel<<<NSTRIPE, NB, 0, stream>>>(Uh, Uv, totH, totV);
        /* note: fallback skips y-scan ordering subtlety — scans are separable,
           row scan after column scan is equivalent; do row scan last */
        /* column-scan offsets + epilogue needs row scan first though, so do
           full ordering: row scan over y */
        /* (fallback path is correctness-only; not expected to run) */
        colscan_finish_kernel<<<NSTRIPE, NB, 0, stream>>>(Uh, Uv, totH, totV, out);
        return; /* NOTE: fallback omits y-scan; only used if ws < 8MB */
    }

    float4* rec  = (float4*)ws;
    float*  Uh   = ws + REC;
    float*  Uv   = Uh + GRID;
    float*  totH = Uv + GRID;
    float*  totV = totH + TOT;
    float*  reps = totV + TOT;
    int nets_per_slice = (NUM_NETS + R - 1) / R;

    bbox_kernel<<<(NUM_NETS + 255) / 256, 256, 0, stream>>>(
        pin_pos, flat_netpin, net_weights, rec);

    tile_accum_kernel<<<NTILES * R, 256, 0, stream>>>(rec, reps, nets_per_slice);

    reduce_rowscan_kernel<<<NB, NB, 0, stream>>>(reps, Uh, Uv, R);

    colscan_partial_kernel<<<NSTRIPE, NB, 0, stream>>>(Uh, Uv, totH, totV);

    colscan_finish_kernel<<<NSTRIPE, NB, 0, stream>>>(Uh, Uv, totH, totV, out);
}

// Round 3
// 104.188 us; speedup vs baseline: 2.1610x; 1.1195x over previous
//
#include <hip/hip_runtime.h>

#define NUM_NETS     100000
#define PINS_PER_NET 5
#define NUM_PINS     (NUM_NETS * PINS_PER_NET)
#define NB           512
#define BIN_H        1.953125f          /* 1000/512, exact in fp32 */
#define INV_H        0.512f             /* 512/1000 */
#define OUT_SCALE    (1.0f / 195.3125f) /* 1/(BIN_SIZE_X * 100 tracks) */

#define TILE         64                 /* bins per tile side */
#define NTX          (NB / TILE)        /* 8 */
#define NTILES       (NTX * NTX)        /* 64 */
#define STRIPE       8                  /* rows per column-scan stripe */
#define NSTRIPE      (NB / STRIPE)      /* 64 */

// ---------------------------------------------------------------------------
// K1: per-net bbox -> 32B record
//   r0 = {xmn, xmx, ymn, ymx}
//   r1 = {wh, wv, pack(kx1,kx2), pack(ky1,ky2)}
// ---------------------------------------------------------------------------
__global__ void bbox_kernel(const float* __restrict__ pin_pos,
                            const int*   __restrict__ flat_netpin,
                            const float* __restrict__ net_weights,
                            float4* __restrict__ rec) {
    int n = blockIdx.x * blockDim.x + threadIdx.x;
    if (n >= NUM_NETS) return;
    float xmn = 1e30f, xmx = -1e30f, ymn = 1e30f, ymx = -1e30f;
#pragma unroll
    for (int p = 0; p < PINS_PER_NET; ++p) {
        int pi  = flat_netpin[n * PINS_PER_NET + p];
        float x = pin_pos[pi];
        float y = pin_pos[NUM_PINS + pi];
        xmn = fminf(xmn, x); xmx = fmaxf(xmx, x);
        ymn = fminf(ymn, y); ymx = fmaxf(ymx, y);
    }
    float w = net_weights[n];
    int kx1 = min(NB - 1, (int)(xmn * INV_H));
    int kx2 = min(NB - 1, (int)(xmx * INV_H));
    int ky1 = min(NB - 1, (int)(ymn * INV_H));
    int ky2 = min(NB - 1, (int)(ymx * INV_H));
    unsigned pkx = (unsigned)kx1 | ((unsigned)kx2 << 16);
    unsigned pky = (unsigned)ky1 | ((unsigned)ky2 << 16);
    rec[2 * n]     = make_float4(xmn, xmx, ymn, ymx);
    rec[2 * n + 1] = make_float4(w / (ymx - ymn), w / (xmx - xmn),
                                 __uint_as_float(pkx), __uint_as_float(pky));
}

// ---------------------------------------------------------------------------
// K2: LDS-privatized tile accumulation. Block = (slice r, tile t), 1024 thr.
// Fast 4-compare reject using pre-packed bin indices; accepted records
// (~6%) run the 4x4 corner stencil with LDS atomics.
// ---------------------------------------------------------------------------
__global__ __launch_bounds__(1024) void tile_accum_kernel(
        const float4* __restrict__ rec,
        float* __restrict__ reps, int nets_per_slice) {
    __shared__ float tile[2][TILE * TILE];          /* 32 KB */
    int t   = blockIdx.x & (NTILES - 1);
    int r   = blockIdx.x >> 6;
    int tx0 = (t >> 3) * TILE;
    int ty0 = (t & 7) * TILE;
    int txh = tx0 + TILE - 1;
    int tyh = ty0 + TILE - 1;

    float4* tf4 = (float4*)&tile[0][0];
#pragma unroll
    for (int k = threadIdx.x; k < 2 * TILE * TILE / 4; k += 1024)
        tf4[k] = make_float4(0.f, 0.f, 0.f, 0.f);
    __syncthreads();

    int n0 = r * nets_per_slice;
    int n1 = min(n0 + nets_per_slice, NUM_NETS);
    for (int n = n0 + (int)threadIdx.x; n < n1; n += 1024) {
        float4 r0 = rec[2 * n];
        float4 r1 = rec[2 * n + 1];
        unsigned pkx = __float_as_uint(r1.z);
        unsigned pky = __float_as_uint(r1.w);
        int kx1 = (int)(pkx & 0xffffu), kx2 = (int)(pkx >> 16);
        int ky1 = (int)(pky & 0xffffu), ky2 = (int)(pky >> 16);
        /* fast reject: stencil x-range [kx1, kx2+1], y-range [ky1, ky2+1] */
        if (kx2 + 1 < tx0 || kx1 > txh) continue;
        if (ky2 + 1 < ty0 || ky1 > tyh) continue;

        float xmn = r0.x, xmx = r0.y, ymn = r0.z, ymx = r0.w;
        float wh = r1.x, wv = r1.y;
        int   xi[4] = { kx1, kx1 + 1, kx2, kx2 + 1 };
        float xb[4] = { (kx1 + 1) * BIN_H - xmn,  xmn - kx1 * BIN_H,
                        xmx - (kx2 + 1) * BIN_H,  kx2 * BIN_H - xmx };
        int   yi[4] = { ky1, ky1 + 1, ky2, ky2 + 1 };
        float yv[4] = { (ky1 + 1) * BIN_H - ymn,  ymn - ky1 * BIN_H,
                        ymx - (ky2 + 1) * BIN_H,  ky2 * BIN_H - ymx };
#pragma unroll
        for (int a = 0; a < 4; ++a) {
            unsigned gx = (unsigned)(xi[a] - tx0);
            if (gx >= TILE) continue;
            float xh = xb[a] * wh, xw = xb[a] * wv;
#pragma unroll
            for (int b = 0; b < 4; ++b) {
                unsigned gy = (unsigned)(yi[b] - ty0);
                if (gy >= TILE) continue;
                int idx = (int)gx * TILE + (int)gy;
                atomicAdd(&tile[0][idx], xh * yv[b]);
                atomicAdd(&tile[1][idx], xw * yv[b]);
            }
        }
    }
    __syncthreads();

    float4* dst = (float4*)(reps + (size_t)blockIdx.x * (2 * TILE * TILE));
#pragma unroll
    for (int k = threadIdx.x; k < 2 * TILE * TILE / 4; k += 1024)
        dst[k] = tf4[k];
}

// ---------------------------------------------------------------------------
// K3: reduce replicas + inclusive scan along y (contiguous). Block = grid row.
// ---------------------------------------------------------------------------
__global__ void reduce_rowscan_kernel(const float* __restrict__ reps,
                                      float* __restrict__ Uh,
                                      float* __restrict__ Uv, int R) {
    __shared__ float sh[NB];
    __shared__ float sv[NB];
    int x   = blockIdx.x;
    int tid = threadIdx.x;                 /* = y */
    int tx = x >> 6, xr = x & (TILE - 1);
    int tl = tx * NTX + (tid >> 6);        /* tile index */
    int off = xr * TILE + (tid & (TILE - 1));
    float h = 0.f, v = 0.f;
    for (int r = 0; r < R; ++r) {
        const float* base = reps + (size_t)(r * NTILES + tl) * (2 * TILE * TILE);
        h += base[off];
        v += base[TILE * TILE + off];
    }
    sh[tid] = h; sv[tid] = v;
    __syncthreads();
#pragma unroll
    for (int o = 1; o < NB; o <<= 1) {
        float a = (tid >= o) ? sh[tid - o] : 0.0f;
        float b = (tid >= o) ? sv[tid - o] : 0.0f;
        __syncthreads();
        sh[tid] += a; sv[tid] += b;
        __syncthreads();
    }
    Uh[x * NB + tid] = sh[tid];
    Uv[x * NB + tid] = sv[tid];
}

// ---------------------------------------------------------------------------
// K4: column-scan stage 1 — per-stripe partial inclusive scans + totals.
// ---------------------------------------------------------------------------
__global__ void colscan_partial_kernel(float* __restrict__ Uh,
                                       float* __restrict__ Uv,
                                       float* __restrict__ totH,
                                       float* __restrict__ totV) {
    int s = blockIdx.x, t = threadIdx.x;   /* t = column */
    float h = 0.f, v = 0.f;
#pragma unroll
    for (int i = 0; i < STRIPE; ++i) {
        int row = s * STRIPE + i;
        h += Uh[row * NB + t];  Uh[row * NB + t] = h;
        v += Uv[row * NB + t];  Uv[row * NB + t] = v;
    }
    totH[s * NB + t] = h;
    totV[s * NB + t] = v;
}

// ---------------------------------------------------------------------------
// K5: column-scan stage 2 — exclusive stripe offsets + fused epilogue.
// ---------------------------------------------------------------------------
__global__ void colscan_finish_kernel(const float* __restrict__ Uh,
                                      const float* __restrict__ Uv,
                                      const float* __restrict__ totH,
                                      const float* __restrict__ totV,
                                      float* __restrict__ out) {
    int s = blockIdx.x, t = threadIdx.x;
    float offh = 0.f, offv = 0.f;
    for (int s2 = 0; s2 < s; ++s2) {
        offh += totH[s2 * NB + t];
        offv += totV[s2 * NB + t];
    }
#pragma unroll
    for (int i = 0; i < STRIPE; ++i) {
        int row = s * STRIPE + i;
        float h = fabsf(Uh[row * NB + t] + offh) * OUT_SCALE;
        float v = fabsf(Uv[row * NB + t] + offv) * OUT_SCALE;
        float r = fmaxf(h, v);
        out[row * NB + t] = fminf(fmaxf(r * r, 0.5f), 2.0f);
    }
}

// ---------------------------------------------------------------------------
// Fallback (tiny workspace only): global-atomic scatter + y row scan.
// ---------------------------------------------------------------------------
__global__ void scatter_kernel(const float* __restrict__ pin_pos,
                               const int*   __restrict__ flat_netpin,
                               const float* __restrict__ net_weights,
                               float* __restrict__ Uh,
                               float* __restrict__ Uv) {
    int n = blockIdx.x * blockDim.x + threadIdx.x;
    if (n >= NUM_NETS) return;
    float xmn = 1e30f, xmx = -1e30f, ymn = 1e30f, ymx = -1e30f;
#pragma unroll
    for (int p = 0; p < PINS_PER_NET; ++p) {
        int pi  = flat_netpin[n * PINS_PER_NET + p];
        float x = pin_pos[pi];
        float y = pin_pos[NUM_PINS + pi];
        xmn = fminf(xmn, x); xmx = fmaxf(xmx, x);
        ymn = fminf(ymn, y); ymx = fmaxf(ymx, y);
    }
    float w  = net_weights[n];
    float wh = w / (ymx - ymn), wv = w / (xmx - xmn);
    int kx1 = min(NB - 1, (int)(xmn * INV_H));
    int kx2 = min(NB - 1, (int)(xmx * INV_H));
    int ky1 = min(NB - 1, (int)(ymn * INV_H));
    int ky2 = min(NB - 1, (int)(ymx * INV_H));
    int   xi[4] = { kx1, kx1 + 1, kx2, kx2 + 1 };
    float xv[4] = { (kx1 + 1) * BIN_H - xmn,  xmn - kx1 * BIN_H,
                    xmx - (kx2 + 1) * BIN_H,  kx2 * BIN_H - xmx };
    int   yi[4] = { ky1, ky1 + 1, ky2, ky2 + 1 };
    float yv[4] = { (ky1 + 1) * BIN_H - ymn,  ymn - ky1 * BIN_H,
                    ymx - (ky2 + 1) * BIN_H,  ky2 * BIN_H - ymx };
#pragma unroll
    for (int a = 0; a < 4; ++a) {
        if (xi[a] >= NB) continue;
#pragma unroll
        for (int b = 0; b < 4; ++b) {
            if (yi[b] >= NB) continue;
            float prod = xv[a] * yv[b];
            int   idx  = xi[a] * NB + yi[b];
            atomicAdd(&Uh[idx], wh * prod);
            atomicAdd(&Uv[idx], wv * prod);
        }
    }
}

__global__ void row_scan_kernel(float* __restrict__ Uh, float* __restrict__ Uv) {
    __shared__ float sh[NB];
    __shared__ float sv[NB];
    int r = blockIdx.x;
    int t = threadIdx.x;
    sh[t] = Uh[r * NB + t];
    sv[t] = Uv[r * NB + t];
    __syncthreads();
#pragma unroll
    for (int off = 1; off < NB; off <<= 1) {
        float a = (t >= off) ? sh[t - off] : 0.0f;
        float b = (t >= off) ? sv[t - off] : 0.0f;
        __syncthreads();
        sh[t] += a; sv[t] += b;
        __syncthreads();
    }
    Uh[r * NB + t] = sh[t];
    Uv[r * NB + t] = sv[t];
}

extern "C" void kernel_launch(void* const* d_in, const int* in_sizes, int n_in,
                              void* d_out, int out_size, void* d_ws, size_t ws_size,
                              hipStream_t stream) {
    const float* pin_pos     = (const float*)d_in[0];
    const int*   flat_netpin = (const int*)d_in[2];
    const float* net_weights = (const float*)d_in[3];
    float* out = (float*)d_out;
    float* ws  = (float*)d_ws;

    /* workspace layout (floats):
       rec[NUM_NETS*8] | Uh[NB*NB] | Uv[NB*NB] | totH | totV | reps[R*...] */
    const size_t REC   = (size_t)NUM_NETS * 8;
    const size_t GRID  = (size_t)NB * NB;
    const size_t TOT   = (size_t)NSTRIPE * NB;
    const size_t REP1  = (size_t)NTILES * 2 * TILE * TILE;   /* 2 MB */
    const size_t fixed = REC + 2 * GRID + 2 * TOT;

    int R = 0;
    for (int cand = 8; cand >= 1; cand >>= 1) {
        if (ws_size >= (fixed + (size_t)cand * REP1) * sizeof(float)) { R = cand; break; }
    }

    if (R == 0) {
        /* tiny-workspace fallback: global-atomic path */
        float* Uh = ws;
        float* Uv = ws + GRID;
        float* totH = Uv + GRID;
        float* totV = totH + TOT;
        hipMemsetAsync(ws, 0, 2 * GRID * sizeof(float), stream);
        scatter_kernel<<<(NUM_NETS + 255) / 256, 256, 0, stream>>>(
            pin_pos, flat_netpin, net_weights, Uh, Uv);
        row_scan_kernel<<<NB, NB, 0, stream>>>(Uh, Uv);
        colscan_partial_kernel<<<NSTRIPE, NB, 0, stream>>>(Uh, Uv, totH, totV);
        colscan_finish_kernel<<<NSTRIPE, NB, 0, stream>>>(Uh, Uv, totH, totV, out);
        return;
    }

    float4* rec  = (float4*)ws;
    float*  Uh   = ws + REC;
    float*  Uv   = Uh + GRID;
    float*  totH = Uv + GRID;
    float*  totV = totH + TOT;
    float*  reps = totV + TOT;
    int nets_per_slice = (NUM_NETS + R - 1) / R;

    bbox_kernel<<<(NUM_NETS + 255) / 256, 256, 0, stream>>>(
        pin_pos, flat_netpin, net_weights, rec);

    tile_accum_kernel<<<NTILES * R, 1024, 0, stream>>>(rec, reps, nets_per_slice);

    reduce_rowscan_kernel<<<NB, NB, 0, stream>>>(reps, Uh, Uv, R);

    colscan_partial_kernel<<<NSTRIPE, NB, 0, stream>>>(Uh, Uv, totH, totV);

    colscan_finish_kernel<<<NSTRIPE, NB, 0, stream>>>(Uh, Uv, totH, totV, out);
}